// Round 9
// baseline (292.659 us; speedup 1.0000x reference)
//
#include <hip/hip_runtime.h>
#include <hip/hip_bf16.h>
#include <stdint.h>

// Problem constants
#define Bsz 2048
#define Ssz 200
#define Dsz 128
#define SP  224

typedef __attribute__((ext_vector_type(8))) short short8;
typedef __attribute__((ext_vector_type(4))) float f32x4;
typedef unsigned short ushort_t;
typedef unsigned int uint_t;

// ---- LDS byte offsets (total 72,192 -> 2 blocks/CU) ----
#define KEYS_OFF   0        // [200][128] bf16, XOR-swizzled  51,200
#define H1S_OFF    51200    // [8 waves][16][64] bf16         16,384
#define SCW_OFF    67584    // [4][224] f32                    3,584
#define C1S_OFF    71168    // [256] f32                       1,024
#define SMEM_BYTES 72192
// aliases into H1S after the tile loop (h1 dead):
#define SCWB_OFF   51200    // [16][256] bf16  8,192
#define COMB_OFF   59392    // [128] f32         512
#define PO2_OFF    59904    // [4][128] f32    2,048

__device__ __forceinline__ ushort_t cvtbf(float x) {
    __hip_bfloat16 h = __float2bfloat16(x);   // RTNE; pairs into v_cvt_pk_bf16_f32
    ushort_t u;
    __builtin_memcpy(&u, &h, 2);
    return u;
}

// ---------- prep: fold W1 (sum/c/diff row-major), transpose Wo, cast W2 ----------
__global__ void prep_kernel(const float* __restrict__ W1, const float* __restrict__ W2,
                            const float* __restrict__ Wo,
                            float* __restrict__ W1sum, float* __restrict__ W1c,
                            float* __restrict__ W1diffR, float* __restrict__ WoT,
                            ushort_t* __restrict__ W2bf) {
    int i = blockIdx.x * blockDim.x + threadIdx.x;
    if (i < 32768) {                       // n in [0,256), j in [0,128)
        int n = i >> 7, j = i & 127;
        float a  = W1[n * 512 + j];        // keys part
        float dd = W1[n * 512 + 384 + j];  // (k - q) part
        W1sum[i] = a + dd;                 // coeff of k
        W1c[i]   = W1[n * 512 + 256 + j];  // coeff of k*q
        W1diffR[i] = W1[n * 512 + 128 + j] - dd;  // coeff of q (row-major)
    }
    if (i < 16384) {                       // WoT[j][d] = Wo[d][j]
        int j = i >> 7, d = i & 127;
        WoT[i] = Wo[d * 128 + j];
    }
    if (i < 8192) W2bf[i] = cvtbf(W2[i]); // flat [h][e][k], k fastest
}

// ---------- fused main kernel: 512 threads, two waves per head ----------
__launch_bounds__(512, 4)
__global__ void attn_kernel(const float* __restrict__ query, const float* __restrict__ keys,
                            const int* __restrict__ kmask,
                            const float* __restrict__ a1, const float* __restrict__ b2,
                            const float* __restrict__ a2, const float* __restrict__ W3,
                            const float* __restrict__ b3, const float* __restrict__ b1,
                            const float* __restrict__ bo,
                            const float* __restrict__ W1sum, const float* __restrict__ W1c,
                            const float* __restrict__ W1diffR,
                            const float* __restrict__ WoT, const ushort_t* __restrict__ W2bf,
                            float* __restrict__ out) {
    extern __shared__ char smem[];
    const int tid = threadIdx.x;
    const int bb  = blockIdx.x;
    const int w    = tid >> 6;          // wave 0..7
    const int h    = w & 3;             // head
    const int half = w >> 2;            // s-half: 0 -> tiles 0-6, 1 -> tiles 7-12
    const int l   = tid & 63;
    const int l15 = l & 15;
    const int lk  = l >> 4;

    float* scw  = (float*)(smem + SCW_OFF);
    float* c1s  = (float*)(smem + C1S_OFF);
    float* comb = (float*)(smem + COMB_OFF);
    float* po2  = (float*)(smem + PO2_OFF);
    const float* kb = keys + (size_t)bb * Ssz * Dsz;

    // ---- phase 0a: stage keys -> bf16 LDS (swizzled), 200 rows ----
    #pragma unroll
    for (int it = 0; it < 13; ++it) {          // 200 rows * 32 float4/row = 6400
        int id = tid + 512 * it;
        if (id < 6400) {
            int row = id >> 5, c4 = id & 31;
            float4 kv = *(const float4*)(kb + (size_t)row * Dsz + c4 * 4);
            uint2 p;
            p.x = (uint_t)cvtbf(kv.x) | ((uint_t)cvtbf(kv.y) << 16);
            p.y = (uint_t)cvtbf(kv.z) | ((uint_t)cvtbf(kv.w) << 16);
            int off = KEYS_OFF + (((row << 8) + (c4 << 3)) ^ ((row & 7) << 4));
            *(uint2*)(smem + off) = p;
        }
    }

    // ---- phase 0b: c1[n] = b1[n] + dot(W1diffR[n], q)  (n = tid < 256) ----
    if (tid < 256) {
        float accc = b1[tid];
        const float4* wr  = (const float4*)(W1diffR + tid * 128);
        const float4* qv4 = (const float4*)(query + bb * 128);
        #pragma unroll 8
        for (int j4 = 0; j4 < 32; ++j4) {
            float4 wvv = wr[j4];
            float4 qq = qv4[j4];
            accc += wvv.x * qq.x + wvv.y * qq.y + wvv.z * qq.z + wvv.w * qq.w;
        }
        c1s[tid] = accc;
    }

    // ---- phase 0c: fold W1eff head-slice into registers (reused ~7x) ----
    short8 bfr[16];                            // [t*4+nt]
    #pragma unroll
    for (int t = 0; t < 4; ++t) {
        const int k0 = t * 32 + lk * 8;
        const float4* pq = (const float4*)(query + bb * 128 + k0);
        float4 q0 = pq[0], q1 = pq[1];
        #pragma unroll
        for (int nt = 0; nt < 4; ++nt) {
            int n = h * 64 + nt * 16 + l15;
            const float4* ps = (const float4*)(W1sum + n * 128 + k0);
            const float4* pc = (const float4*)(W1c + n * 128 + k0);
            float4 s0 = ps[0], s1 = ps[1];
            float4 c0 = pc[0], c1f = pc[1];
            short8 ov;
            ov[0] = (short)cvtbf(s0.x + c0.x * q0.x);
            ov[1] = (short)cvtbf(s0.y + c0.y * q0.y);
            ov[2] = (short)cvtbf(s0.z + c0.z * q0.z);
            ov[3] = (short)cvtbf(s0.w + c0.w * q0.w);
            ov[4] = (short)cvtbf(s1.x + c1f.x * q1.x);
            ov[5] = (short)cvtbf(s1.y + c1f.y * q1.y);
            ov[6] = (short)cvtbf(s1.z + c1f.z * q1.z);
            ov[7] = (short)cvtbf(s1.w + c1f.w * q1.w);
            bfr[t * 4 + nt] = ov;
        }
    }

    // per-wave layer-2/3 constants
    const float a1v = a1[h];
    const float a2v = a2[h];
    const float b3v = b3[h];
    float b2v[2], w3v[2];
    #pragma unroll
    for (int nt = 0; nt < 2; ++nt) {
        b2v[nt] = b2[h * 32 + nt * 16 + l15];
        w3v[nt] = W3[h * 32 + nt * 16 + l15];
    }
    short8 w2f[2][2];
    #pragma unroll
    for (int kt = 0; kt < 2; ++kt)
        #pragma unroll
        for (int nt = 0; nt < 2; ++nt)
            w2f[kt][nt] = *(const short8*)(W2bf + h * 2048 + (nt * 16 + l15) * 64 + kt * 32 + lk * 8);

    __syncthreads();   // barrier 1: keys + c1 staged

    float c1v[4];
    #pragma unroll
    for (int nt = 0; nt < 4; ++nt) c1v[nt] = c1s[h * 64 + nt * 16 + l15];

    const f32x4 fz = {0.f, 0.f, 0.f, 0.f};
    char* h1b = smem + H1S_OFF + w * 2048;     // wave-private [16][64] bf16

    // ---- this wave's tiles (7 or 6 of 13); wave-local pipeline ----
    #pragma unroll 1
    for (int mi = 0; mi < 7; ++mi) {
        int m = half * 7 + mi;
        if (m < 13) {
            f32x4 acc[4];
            #pragma unroll
            for (int nt = 0; nt < 4; ++nt) acc[nt] = fz;

            #pragma unroll
            for (int t = 0; t < 4; ++t) {
                int row = m * 16 + l15;
                row = (row < Ssz) ? row : (Ssz - 1);   // clamp tile 12; masked later
                int off = KEYS_OFF + (((row << 8) + (t * 64 + lk * 16)) ^ ((row & 7) << 4));
                short8 afr = *(const short8*)(smem + off);
                #pragma unroll
                for (int nt = 0; nt < 4; ++nt)
                    acc[nt] = __builtin_amdgcn_mfma_f32_16x16x32_bf16(afr, bfr[t * 4 + nt], acc[nt], 0, 0, 0);
            }

            // leaky(h1)+c1 -> wave-private scratch (bf16, XOR-swizzled rows)
            #pragma unroll
            for (int nt = 0; nt < 4; ++nt) {
                #pragma unroll
                for (int r = 0; r < 4; ++r) {
                    float v = acc[nt][r] + c1v[nt];
                    v = (v >= 0.f) ? v : a1v * v;
                    int lr = lk * 4 + r;
                    int colb = (nt * 16 + l15) * 2;
                    *(ushort_t*)(h1b + lr * 128 + (colb ^ ((lr & 7) << 4))) = cvtbf(v);
                }
            }

            // layer 2+3 (wave-local; per-wave DS FIFO + data deps handle RAW/WAR)
            f32x4 acc2[2];
            acc2[0] = fz; acc2[1] = fz;
            #pragma unroll
            for (int kt = 0; kt < 2; ++kt) {
                short8 afr2 = *(const short8*)(h1b + l15 * 128 + ((kt * 64 + lk * 16) ^ ((l15 & 7) << 4)));
                #pragma unroll
                for (int nt = 0; nt < 2; ++nt)
                    acc2[nt] = __builtin_amdgcn_mfma_f32_16x16x32_bf16(afr2, w2f[kt][nt], acc2[nt], 0, 0, 0);
            }
            #pragma unroll
            for (int r = 0; r < 4; ++r) {
                float sum = 0.f;
                #pragma unroll
                for (int nt = 0; nt < 2; ++nt) {
                    float v = acc2[nt][r] + b2v[nt];
                    v = (v >= 0.f) ? v : a2v * v;
                    sum += v * w3v[nt];
                }
                sum += __shfl_xor(sum, 1);
                sum += __shfl_xor(sum, 2);
                sum += __shfl_xor(sum, 4);
                sum += __shfl_xor(sum, 8);
                if (l15 == 0) {
                    int sg = m * 16 + lk * 4 + r;
                    if (sg < Ssz) {
                        float tw = __expf(0.1f * (float)(sg - (Ssz - 1)));
                        float sc = (sum + b3v) * tw;
                        scw[h * SP + sg] = kmask[bb * Ssz + sg] ? sc : -1.0e9f;
                    }
                }
            }
        }
    }
    __syncthreads();   // barrier 2: all scores written (both halves)

    // ---- softmax, waves 0-3 (head = w); packs bf16 weights too ----
    if (w < 4) {
        float wv[4], xv[4];
        float mx = -3.0e38f;
        #pragma unroll
        for (int i = 0; i < 4; ++i) {
            int s = l + 64 * i;
            xv[i] = (s < Ssz) ? scw[w * SP + s] : -1.0e30f;
            mx = fmaxf(mx, xv[i]);
        }
        #pragma unroll
        for (int m = 1; m < 64; m <<= 1) mx = fmaxf(mx, __shfl_xor(mx, m));
        float sm = 0.f;
        #pragma unroll
        for (int i = 0; i < 4; ++i) {
            int s = l + 64 * i;
            wv[i] = (s < Ssz) ? __expf(xv[i] - mx) : 0.f;
            sm += wv[i];
        }
        #pragma unroll
        for (int m = 1; m < 64; m <<= 1) sm += __shfl_xor(sm, m);
        float inv = 1.0f / sm;
        #pragma unroll
        for (int i = 0; i < 4; ++i) {
            int s = l + 64 * i;
            wv[i] *= inv;
            if (s < Ssz) scw[w * SP + s] = wv[i];   // f32 weights (avg out)
            // bf16 weights row w of scwb [16][256]
            *(ushort_t*)(smem + SCWB_OFF + w * 512 + s * 2) =
                (s < Ssz) ? cvtbf(wv[i]) : (ushort_t)0;
        }
    } else {
        // zero scwb rows 4..15 (12 rows * 512 B = 1536 u32) with waves 4-7
        uint_t* zb = (uint_t*)(smem + SCWB_OFF + 4 * 512);
        int t4 = tid - 256;
        #pragma unroll
        for (int k = 0; k < 6; ++k) zb[t4 + 256 * k] = 0;
    }
    __syncthreads();   // barrier 3: scwb ready; h1 region dead

    // avg_weights output
    if (tid < Ssz) {
        float aw = 0.25f * (scw[tid] + scw[SP + tid] + scw[2 * SP + tid] + scw[3 * SP + tid]);
        out[Bsz * Dsz + bb * Ssz + tid] = aw;
    }

    // ---- PV via MFMA: A = scwb (rows=heads), B = keys; wave w -> d cols [16w, 16w+16) ----
    {
        f32x4 acc4 = fz;
        #pragma unroll
        for (int t7 = 0; t7 < 7; ++t7) {
            int kbase = t7 * 32 + lk * 8;
            short8 afr = *(const short8*)(smem + SCWB_OFF + l15 * 512 + kbase * 2);
            short8 bfr2;
            #pragma unroll
            for (int j = 0; j < 8; ++j) {
                int s = kbase + j;
                ushort_t kv = 0;
                if (s < Ssz) {
                    kv = *(const ushort_t*)(smem + KEYS_OFF +
                          ((((s << 8) + ((16 * w + l15) << 1))) ^ ((s & 7) << 4)));
                }
                bfr2[j] = (short)kv;
            }
            acc4 = __builtin_amdgcn_mfma_f32_16x16x32_bf16(afr, bfr2, acc4, 0, 0, 0);
        }
        if (lk == 0)
            comb[16 * w + l15] = 0.25f * (acc4[0] + acc4[1] + acc4[2] + acc4[3]);
    }
    __syncthreads();   // barrier 4: comb ready

    // ---- output projection: 512 threads, 4 parts of 32 j each ----
    {
        int d = tid & 127, part = tid >> 7;
        float o = 0.f;
        const float* wp = WoT + (size_t)part * 32 * 128 + d;
        #pragma unroll 8
        for (int j = 0; j < 32; ++j) o += comb[part * 32 + j] * wp[j * 128];
        po2[part * 128 + d] = o;
    }
    __syncthreads();   // barrier 5
    if (tid < 128) {
        out[bb * Dsz + tid] = bo[tid] + po2[tid] + po2[128 + tid] + po2[256 + tid] + po2[384 + tid];
    }
}

// ws layout (bytes): W1sum 131072 | W1c 131072 | W1diffR 131072 | WoT 65536 | W2bf 16384
extern "C" void kernel_launch(void* const* d_in, const int* in_sizes, int n_in,
                              void* d_out, int out_size, void* d_ws, size_t ws_size,
                              hipStream_t stream) {
    const float* query = (const float*)d_in[0];
    const float* keys  = (const float*)d_in[1];
    const int*   kmask = (const int*)d_in[2];
    const float* W1    = (const float*)d_in[3];
    const float* b1    = (const float*)d_in[4];
    const float* a1    = (const float*)d_in[5];
    const float* W2    = (const float*)d_in[6];
    const float* b2    = (const float*)d_in[7];
    const float* a2    = (const float*)d_in[8];
    const float* W3    = (const float*)d_in[9];
    const float* b3    = (const float*)d_in[10];
    const float* Wo    = (const float*)d_in[11];
    const float* bo    = (const float*)d_in[12];
    float* out = (float*)d_out;

    char* ws = (char*)d_ws;
    float*    W1sum   = (float*)(ws);
    float*    W1c     = (float*)(ws + 131072);
    float*    W1diffR = (float*)(ws + 262144);
    float*    WoT     = (float*)(ws + 393216);
    ushort_t* W2bf    = (ushort_t*)(ws + 458752);

    hipFuncSetAttribute(reinterpret_cast<const void*>(attn_kernel),
                        hipFuncAttributeMaxDynamicSharedMemorySize, SMEM_BYTES);

    prep_kernel<<<128, 256, 0, stream>>>(W1, W2, Wo, W1sum, W1c, W1diffR, WoT, W2bf);
    attn_kernel<<<Bsz, 512, SMEM_BYTES, stream>>>(query, keys, kmask, a1, b2, a2, W3, b3, b1, bo,
                                                  W1sum, W1c, W1diffR, WoT, W2bf, out);
}